// Round 15
// baseline (124.302 us; speedup 1.0000x reference)
//
#include <hip/hip_runtime.h>

#define H 4
#define DH 64
#define D 256
#define NN 1024
#define BB 8

typedef __attribute__((ext_vector_type(8))) short short8;   // 8 bf16
typedef __attribute__((ext_vector_type(4))) short short4v;  // 4 bf16
typedef __attribute__((ext_vector_type(4))) float f32x4;    // MFMA C/D frag

__device__ __forceinline__ short f2bf(float f) {
    union { float f; unsigned u; } v; v.f = f;
    unsigned r = v.u + 0x7FFFu + ((v.u >> 16) & 1u);   // RNE
    return (short)(r >> 16);
}
__device__ __forceinline__ float bf2f(short s) {
    union { float f; unsigned u; } v;
    v.u = ((unsigned)(unsigned short)s) << 16;
    return v.f;
}

// ---------- Kernel 0: W (f32, DxD) -> Wb (bf16, same layout) -----------------
__global__ __launch_bounds__(256) void wcvt(const float* __restrict__ W,
                                            short* __restrict__ Wb) {
    int i = (blockIdx.x * 256 + threadIdx.x) * 4;
    float4 f = *(const float4*)(W + i);
    short4v o; o[0] = f2bf(f.x); o[1] = f2bf(f.y); o[2] = f2bf(f.z); o[3] = f2bf(f.w);
    *(short4v*)(Wb + i) = o;
}

// ---------- Kernel 1: proj via MFMA -> ht2 (packed B-frag layout) ------------
// ht2[b][h][n][jc][l][e] : element = h[i = jc*32 + (l>>4)*8 + e][d = 64h+16n+(l&15)]
__global__ __launch_bounds__(256) void proj_kernel(
    const float* __restrict__ nf, const short* __restrict__ Wb,
    const float* __restrict__ aw, short* __restrict__ ht2,
    float* __restrict__ slT, float* __restrict__ srT) {
    int t = threadIdx.x;
    int lane = t & 63, wv = t >> 6;        // wave = head
    int col = lane & 15, g = lane >> 4;
    long i0 = (long)blockIdx.x * 16;
    int b = (int)(i0 >> 10);
    int il0 = (int)(i0 & (NN - 1));

    f32x4 C[4] = {};
    const float* arow  = nf + (i0 + col) * D;
    const short* wrow0 = Wb + (long)(64 * wv + col) * D;   // n adds 16*D

    #pragma unroll
    for (int kk = 0; kk < 8; ++kk) {
        int k0 = kk * 32 + g * 8;
        float4 f0 = *(const float4*)(arow + k0);
        float4 f1 = *(const float4*)(arow + k0 + 4);
        short8 a;
        a[0]=f2bf(f0.x); a[1]=f2bf(f0.y); a[2]=f2bf(f0.z); a[3]=f2bf(f0.w);
        a[4]=f2bf(f1.x); a[5]=f2bf(f1.y); a[6]=f2bf(f1.z); a[7]=f2bf(f1.w);
        #pragma unroll
        for (int n = 0; n < 4; ++n) {
            short8 bfr = *(const short8*)(wrow0 + (long)n * 16 * D + k0);
            C[n] = __builtin_amdgcn_mfma_f32_16x16x32_bf16(a, bfr, C[n], 0, 0, 0);
        }
    }

    // epilogue: ht2 packed stores + sl/sr head dots
    float wlv[4], wrv[4];
    #pragma unroll
    for (int n = 0; n < 4; ++n) {
        wlv[n] = aw[16 * n + col];
        wrv[n] = aw[DH + 16 * n + col];
    }
    float slp[4] = {0.f, 0.f, 0.f, 0.f}, srp[4] = {0.f, 0.f, 0.f, 0.f};
    #pragma unroll
    for (int n = 0; n < 4; ++n) {
        long hb = (((long)b * H + wv) * 4 + n) * (32 * 512);
        #pragma unroll
        for (int r = 0; r < 4; ++r) {
            float hv = C[n][r];                       // row i = il0 + 4g + r
            int i = il0 + 4 * g + r;
            long idx = hb + (long)(i >> 5) * 512 + (((i >> 3) & 3) * 16 + col) * 8 + (i & 7);
            ht2[idx] = f2bf(hv);
            slp[r] += hv * wlv[n];
            srp[r] += hv * wrv[n];
        }
    }
    #pragma unroll
    for (int r = 0; r < 4; ++r) {
        float x = slp[r], y = srp[r];
        #pragma unroll
        for (int o = 1; o < 16; o <<= 1) {
            x += __shfl_xor(x, o, 64);
            y += __shfl_xor(y, o, 64);
        }
        slp[r] = x; srp[r] = y;
    }
    if (col == 0) {
        long sbase = ((long)b * H + wv) * NN + il0 + 4 * g;
        #pragma unroll
        for (int r = 0; r < 4; ++r) {
            slT[sbase + r] = slp[r];
            srT[sbase + r] = srp[r];
        }
    }
}

// ---------- Kernel 2: staged scores->exp->MFMA PV, 16 waves/block ------------
// 1024 thr = 16 waves: wave = (head, j-quarter). Full occupancy (32 waves/CU).
__global__ __launch_bounds__(1024, 8) void attn_kernel(
    const float* __restrict__ nf, const float* __restrict__ adj,
    const float* __restrict__ aw, const float* __restrict__ bias,
    const short* __restrict__ ht2, const float* __restrict__ slT,
    const float* __restrict__ srT, float* __restrict__ out) {
    __shared__ __align__(16) char lds[50176];
    // [0,32768)      adjL  bf16 [16 rows][1024 j]  (byte ^= (row&7)<<4 per 16B)
    // [32768,49152)  srL   f32  [4 heads][1024 j]
    // [0,49152)      Cbuf  f32x4 [3 jq-1][4 head][4 n][64]  (aliased AFTER barrier)
    // [49152,50176)  Ssum  f32  [4 jq][4 head][16 row]
    float* srL  = (float*)(lds + 32768);
    f32x4* Cbuf = (f32x4*)lds;
    float* Ssum = (float*)(lds + 49152);

    int t = threadIdx.x;
    int lane = t & 63, wv = t >> 6;            // wv in 0..15

    int bid = blockIdx.x;
    int swz = (bid & 7) * 64 + (bid >> 3);     // 512 blocks, 8 XCDs, bijective
    long i0 = (long)swz * 16;
    int b = (int)(i0 >> 10);
    int il0 = (int)(i0 & (NN - 1));

    float we = aw[2 * DH];

    // ---- Phase A: wave wv stages adj row wv (masked bf16); waves 0-3 stage sr
    {
        int row = wv;
        const float* arow = adj + ((long)b * NN + il0 + row) * NN;
        char* dst = lds + row * 2048;
        int sw = (row & 7) << 4;
        #pragma unroll
        for (int sp = 0; sp < 4; ++sp) {
            float4 f = *(const float4*)(arow + sp * 256 + lane * 4);
            short4v o;
            o[0] = (f.x <= 1e-5f) ? (short)0xBF80 : f2bf(f.x);
            o[1] = (f.y <= 1e-5f) ? (short)0xBF80 : f2bf(f.y);
            o[2] = (f.z <= 1e-5f) ? (short)0xBF80 : f2bf(f.z);
            o[3] = (f.w <= 1e-5f) ? (short)0xBF80 : f2bf(f.w);
            *(short4v*)(dst + ((sp * 512 + lane * 8) ^ sw)) = o;
        }
    }
    if (wv < 4) {
        const float* srrow = srT + ((long)b * H + wv) * NN;
        float* d2 = srL + wv * 1024;
        #pragma unroll
        for (int sp = 0; sp < 4; ++sp)
            *(float4*)(d2 + sp * 256 + lane * 4) =
                *(const float4*)(srrow + sp * 256 + lane * 4);
    }
    __syncthreads();

    // ---- Phase B: wave (head, jq) covers kt = jq*8 .. jq*8+7
    int head = wv & 3, jq = wv >> 2;
    int col = lane & 15, g = lane >> 4;
    float slv = slT[((long)b * H + head) * NN + il0 + col];
    const short* hb = ht2 + (((long)b * H + head) * 4) * (32 * 512);
    const char* adjbase = lds + col * 2048;
    int asw = (col & 7) << 4;
    const float* srh = srL + head * 1024;

    f32x4 C[4] = {};
    float sum = 0.f;

    #pragma unroll
    for (int tt = 0; tt < 8; ++tt) {
        int kt = jq * 8 + tt;
        short8 araw = *(const short8*)(adjbase + ((kt * 64 + g * 16) ^ asw));
        float4 s0 = *(const float4*)(srh + kt * 32 + g * 8);
        float4 s1 = *(const float4*)(srh + kt * 32 + g * 8 + 4);
        short8 b0 = *(const short8*)(hb + (0 * 32 + kt) * 512 + lane * 8);
        short8 b1 = *(const short8*)(hb + (1 * 32 + kt) * 512 + lane * 8);
        short8 b2 = *(const short8*)(hb + (2 * 32 + kt) * 512 + lane * 8);
        short8 b3 = *(const short8*)(hb + (3 * 32 + kt) * 512 + lane * 8);
        float sv[8] = {s0.x, s0.y, s0.z, s0.w, s1.x, s1.y, s1.z, s1.w};
        short8 af;
        #pragma unroll
        for (int e = 0; e < 8; ++e) {
            float avv = bf2f(araw[e]);
            float s = slv + sv[e] + avv * we;
            s = fmaxf(s, 0.2f * s);                 // leaky 0.2
            float p = __expf(s);                    // no max-sub: |s| <~ 7
            p = (avv < 0.f) ? 0.f : p;              // sentinel mask
            sum += p;
            af[e] = f2bf(p);
        }
        C[0] = __builtin_amdgcn_mfma_f32_16x16x32_bf16(af, b0, C[0], 0, 0, 0);
        C[1] = __builtin_amdgcn_mfma_f32_16x16x32_bf16(af, b1, C[1], 0, 0, 0);
        C[2] = __builtin_amdgcn_mfma_f32_16x16x32_bf16(af, b2, C[2], 0, 0, 0);
        C[3] = __builtin_amdgcn_mfma_f32_16x16x32_bf16(af, b3, C[3], 0, 0, 0);
    }

    sum += __shfl_xor(sum, 16, 64);
    sum += __shfl_xor(sum, 32, 64);
    if (g == 0) Ssum[(jq * 4 + head) * 16 + col] = sum;
    __syncthreads();                     // all adjL/srL reads complete
    if (jq != 0) {
        #pragma unroll
        for (int n = 0; n < 4; ++n)
            Cbuf[((jq - 1) * 16 + head * 4 + n) * 64 + lane] = C[n];  // aliases staging
    }
    __syncthreads();

    if (jq == 0) {
        float rinv[4];
        #pragma unroll
        for (int r = 0; r < 4; ++r) {
            int row = 4 * g + r;
            rinv[r] = 1.f / (Ssum[(0 * 4 + head) * 16 + row] +
                             Ssum[(1 * 4 + head) * 16 + row] +
                             Ssum[(2 * 4 + head) * 16 + row] +
                             Ssum[(3 * 4 + head) * 16 + row]);
        }
        #pragma unroll
        for (int n = 0; n < 4; ++n) {
            int d = 64 * head + 16 * n + col;
            float bv = bias[d];
            f32x4 c1 = Cbuf[(0 * 16 + head * 4 + n) * 64 + lane];
            f32x4 c2 = Cbuf[(1 * 16 + head * 4 + n) * 64 + lane];
            f32x4 c3 = Cbuf[(2 * 16 + head * 4 + n) * 64 + lane];
            #pragma unroll
            for (int r = 0; r < 4; ++r) {
                long row = i0 + 4 * g + r;
                float val = (C[n][r] + c1[r] + c2[r] + c3[r]) * rinv[r];
                float x = nf[row * D + d] + val + bv;
                x = fmaxf(x, 0.5f * x);             // leaky 0.5
                out[row * D + d] = x;
            }
        }
    }
}

extern "C" void kernel_launch(void* const* d_in, const int* in_sizes, int n_in,
                              void* d_out, int out_size, void* d_ws, size_t ws_size,
                              hipStream_t stream) {
    const float* nf   = (const float*)d_in[0];
    const float* adj  = (const float*)d_in[1];
    const float* W    = (const float*)d_in[2];
    const float* aw   = (const float*)d_in[3];
    const float* bias = (const float*)d_in[4];
    float* out = (float*)d_out;

    char* ws = (char*)d_ws;
    short* ht2 = (short*)ws;                                   // 4 MB
    float* slT = (float*)(ws + (size_t)BB * D * NN * 2);       // 32 KB
    float* srT = slT + (size_t)BB * H * NN;                    // 32 KB
    short* Wb  = (short*)(srT + (size_t)BB * H * NN);          // 128 KB

    wcvt<<<D * D / 1024, 256, 0, stream>>>(W, Wb);
    proj_kernel<<<(BB * NN) / 16, 256, 0, stream>>>(nf, Wb, aw, ht2, slT, srT);
    attn_kernel<<<(BB * NN) / 16, 1024, 0, stream>>>(nf, adj, aw, bias, ht2, slT, srT, out);
}